// Round 14
// baseline (175.454 us; speedup 1.0000x reference)
//
#include <hip/hip_runtime.h>
#include <hip/hip_bf16.h>

#define DEVINL static __device__ __forceinline__

typedef __attribute__((ext_vector_type(8))) short bf16x8;
typedef __attribute__((ext_vector_type(8))) unsigned short us8;
typedef __attribute__((ext_vector_type(4))) float f32x4;
typedef __attribute__((ext_vector_type(4))) unsigned short us4;

DEVINL float siluf(float x) { return x / (1.0f + __expf(-x)); }
DEVINL unsigned short bfb(float x) { __hip_bfloat16 h = __float2bfloat16(x); return *(unsigned short*)&h; }
DEVINL float b2f(unsigned short u) { return __uint_as_float(((unsigned int)u) << 16); }

// ===================== fused prep kernel =====================
// blocks [0,25): wfrag | [25,281): km(bf16) | [281,1049): projt | [1049,2073): pft | [2073,2585): hq
__global__ __launch_bounds__(256) void prep_all(
    const float* __restrict__ invs, const float* __restrict__ cond_invs,
    const float* __restrict__ cond_equis,
    const float* __restrict__ q_w, const float* __restrict__ q_b,
    const float* __restrict__ k_w, const float* __restrict__ k_b,
    const float* __restrict__ w1, const float* __restrict__ b1,
    const float* __restrict__ w2,
    const float* __restrict__ equi_in_w,
    const float* __restrict__ inv_in_w, const float* __restrict__ inv_in_b,
    unsigned short* __restrict__ w1f, unsigned short* __restrict__ w2f,
    unsigned short* __restrict__ kmb, float* __restrict__ hq,
    float* __restrict__ projt, float* __restrict__ pft) {
  __shared__ float smem_f[1024];
  const int blk = blockIdx.x, tid = threadIdx.x;

  if (blk < 25) {   // ---- weights to fragment order ----
    const int g = blk;
    if (g < 16) {
      #pragma unroll
      for (int e2 = 0; e2 < 16; ++e2) {
        const int flat = tid * 16 + e2;
        const int kk = flat >> 9, rem = flat & 511, ln = rem >> 3, e = rem & 7;
        const int c = g * 16 + (ln & 15);
        const int k = kk * 32 + (ln >> 4) * 8 + e;
        w1f[(size_t)g * 4096 + flat] = bfb(w1[(size_t)k * 256 + c]);
      }
    } else {
      const int t = g - 16;
      #pragma unroll
      for (int e2 = 0; e2 < 16; ++e2) {
        const int flat = tid * 16 + e2;
        const int kk = flat >> 9, rem = flat & 511, ln = rem >> 3, e = rem & 7;
        const int c = t * 16 + (ln & 15);
        const int k = kk * 32 + (ln >> 4) * 8 + e;
        w2f[(size_t)t * 4096 + flat] = bfb(w2[(size_t)k * 144 + c]);
      }
    }
    return;
  }
  if (blk < 281) {  // ---- kmb = bf16(cond_invs @ k_w + k_b) (4 rows/block) ----
    const int row = (blk - 25) * 4 + (tid >> 6), c = tid & 63;
    float* srow = smem_f + (tid >> 6) * 256;
    for (int k = c; k < 256; k += 64) srow[k] = cond_invs[(size_t)row * 256 + k];
    __syncthreads();
    float a = k_b[c];
    for (int k = 0; k < 256; ++k) a += srow[k] * k_w[(size_t)k * 64 + c];
    kmb[(size_t)row * 64 + c] = bfb(a);
    return;
  }
  if (blk < 1049) { // ---- projt (k-major), 4 rows/block ----
    const int r = (blk - 281) * 4 + (tid >> 6), c = tid & 63;
    float* srow = smem_f + (tid >> 6) * 64;
    srow[c] = cond_equis[(size_t)r * 64 + c];
    __syncthreads();
    float a = 0.f;
    for (int k = 0; k < 64; ++k) a += srow[k] * equi_in_w[(size_t)k * 64 + c];
    const int b = r / 1536, rr = r % 1536, kn = rr / 3, x = rr % 3;
    projt[((size_t)(b * 3 + x) * 64 + c) * 512 + kn] = a;
    return;
  }
  if (blk < 2073) { // ---- pft (k-major) ----
    const int r = blk - 1049, b = r >> 9, kn = r & 511;
    smem_f[tid] = cond_invs[(size_t)r * 256 + tid];
    __syncthreads();
    float a = inv_in_b[tid];
    for (int k = 0; k < 256; ++k) a += smem_f[k] * inv_in_w[(size_t)k * 256 + tid];
    pft[((size_t)(b * 256) + tid) * 512 + kn] = a;
    return;
  }
  {   // ---- hq[bq][256] = b1 + (invs@q_w + q_b) @ w1[0:64,:] ----
    const int r = blk - 2073;
    smem_f[tid] = invs[(size_t)r * 256 + tid];
    __syncthreads();
    if (tid < 64) {
      float a = q_b[tid];
      for (int k = 0; k < 256; ++k) a += smem_f[k] * q_w[(size_t)k * 64 + tid];
      smem_f[256 + tid] = a;
    }
    __syncthreads();
    float a = b1[tid];
    for (int d = 0; d < 64; ++d) a += smem_f[256 + d] * w1[(size_t)d * 256 + tid];
    hq[(size_t)r * 256 + tid] = a;
  }
}

// ===================== main message kernel: 128-row tiles, 8 waves =====================
// grid = 2048; lb = (bid&7)*256 + bid>>3 (XCD-contiguous); bq = lb>>2, k0 = (lb&3)*128.
// wave (wm,wn): wm = row half, wn = col quarter; per-wave tile 64x64 (same regs as r9).
__global__ __launch_bounds__(512, 2) void msg_kernel(
    const float* __restrict__ equis, const float* __restrict__ cond_equis,
    const float* __restrict__ edges,
    const float* __restrict__ hq, const unsigned short* __restrict__ kmb,
    const unsigned short* __restrict__ w1f,
    const unsigned short* __restrict__ w2f, const float* __restrict__ b2,
    float* __restrict__ edge_out, __hip_bfloat16* __restrict__ sct) {
  __shared__ __align__(16) unsigned short buf[128][264];   // feats -> h -> bounce (aliased), 67584 B
  unsigned short (*score_s)[92] = (unsigned short (*)[92])&buf[0][0];          // 128*184 = 23552 B
  float (*edge_s)[68]           = (float (*)[68])((char*)&buf[0][0] + 23552);  // 128*272 = 34816 -> 58368 <= 67584

  const int lb = ((blockIdx.x & 7) << 8) + (blockIdx.x >> 3);   // bijective for 2048
  const int bq = lb >> 2;             // b*256+q
  const int b  = bq >> 8;
  const int k0 = (lb & 3) * 128;
  const int tid = threadIdx.x;
  const int lane = tid & 63, wv = tid >> 6;
  const int wn = wv & 3, wm = wv >> 2;   // col quarter, row half
  const int lj  = lane & 15;
  const int lkb = (lane >> 4) * 8;
  const int lr4 = (lane >> 4) * 4;

  // ---- stage km bf16 copy (cols 0..63), edges (cols 128..191), dot (cols 64..127) ----
  #pragma unroll
  for (int it = 0; it < 2; ++it) {
    const int flat = it * 512 + tid, row = flat >> 3, seg = flat & 7;
    *(us8*)&buf[row][seg * 8] = *(const us8*)&kmb[((size_t)(b * 512 + k0 + row)) * 64 + seg * 8];
  }
  #pragma unroll
  for (int it = 0; it < 4; ++it) {
    const int flat = it * 512 + tid, row = flat >> 4, seg = flat & 15;
    const float4 v = *(const float4*)&edges[((size_t)bq * 512 + k0 + row) * 64 + seg * 4];
    us4 u = { bfb(v.x), bfb(v.y), bfb(v.z), bfb(v.w) };
    *(us4*)&buf[row][128 + seg * 4] = u;
  }
  {
    const int r = tid >> 2, dseg = tid & 3;     // 128 rows x 4 col-segments
    const float* cer = cond_equis + ((size_t)(b * 512 + k0 + r)) * 192 + dseg * 16;
    const float* eqr = equis + (size_t)bq * 192 + dseg * 16;
    float dv[16];
    #pragma unroll
    for (int j = 0; j < 16; ++j) dv[j] = 0.f;
    #pragma unroll
    for (int sec = 0; sec < 3; ++sec) {
      #pragma unroll
      for (int q4 = 0; q4 < 4; ++q4) {
        const float4 cv = *(const float4*)&cer[sec * 64 + q4 * 4];
        const float4 ev = *(const float4*)&eqr[sec * 64 + q4 * 4];   // quad-broadcast, L2/L3-hot
        dv[q4 * 4 + 0] += cv.x * ev.x;
        dv[q4 * 4 + 1] += cv.y * ev.y;
        dv[q4 * 4 + 2] += cv.z * ev.z;
        dv[q4 * 4 + 3] += cv.w * ev.w;
      }
    }
    us8 o0, o1;
    #pragma unroll
    for (int j = 0; j < 8; ++j) { o0[j] = bfb(dv[j]); o1[j] = bfb(dv[8 + j]); }
    *(us8*)&buf[r][64 + dseg * 16] = o0;
    *(us8*)&buf[r][64 + dseg * 16 + 8] = o1;
  }
  __syncthreads();

// weight fragments: GEMM1 uses w1 rows 64..255 -> w1f kk index (KK+2)
#define LW1(BUF, KK) { \
    _Pragma("unroll") for (int ct = 0; ct < 4; ++ct) \
      BUF[ct] = *(const bf16x8*)&w1f[((size_t)(((wn * 4 + ct) * 8 + ((KK) + 2)) * 64) + lane) * 8]; }

#define G1STEP(KK, CUR, NXT, DOPF) { \
    if (DOPF) { LW1(NXT, (KK) + 1); } \
    bf16x8 fbv[4]; \
    _Pragma("unroll") for (int rt = 0; rt < 4; ++rt) \
      fbv[rt] = *(const bf16x8*)&buf[wm * 64 + rt * 16 + lj][(KK) * 32 + lkb]; \
    _Pragma("unroll") for (int ct = 0; ct < 4; ++ct) \
      _Pragma("unroll") for (int rt = 0; rt < 4; ++rt) \
        acc[ct][rt] = __builtin_amdgcn_mfma_f32_16x16x32_bf16(CUR[ct], fbv[rt], acc[ct][rt], 0, 0, 0); }

#define LW2(BUF, KK) { \
    _Pragma("unroll") for (int it = 0; it < 3; ++it) { \
      const int t = it * 4 + wn; \
      if (t < 9) BUF[it] = *(const bf16x8*)&w2f[((size_t)((t * 8 + (KK)) * 64) + lane) * 8]; } }

#define G2STEP(KK, CUR, NXT, DOPF) { \
    if (DOPF) { LW2(NXT, (KK) + 1); } \
    bf16x8 fbv[4]; \
    _Pragma("unroll") for (int rt = 0; rt < 4; ++rt) \
      fbv[rt] = *(const bf16x8*)&buf[wm * 64 + rt * 16 + lj][(KK) * 32 + lkb]; \
    _Pragma("unroll") for (int it = 0; it < 3; ++it) { \
      const int t = it * 4 + wn; \
      if (t < 9) { \
        _Pragma("unroll") for (int rt = 0; rt < 4; ++rt) \
          a2[it][rt] = __builtin_amdgcn_mfma_f32_16x16x32_bf16(CUR[it], fbv[rt], a2[it][rt], 0, 0, 0); \
      } } }

  // ---- GEMM1: acc init from hq (qm contribution + b1), 6 kk steps over buf ----
  f32x4 acc[4][4];
  #pragma unroll
  for (int ct = 0; ct < 4; ++ct) {
    const float4 hv = *(const float4*)&hq[(size_t)bq * 256 + wn * 64 + ct * 16 + lr4];
    #pragma unroll
    for (int rt = 0; rt < 4; ++rt) { acc[ct][rt][0] = hv.x; acc[ct][rt][1] = hv.y; acc[ct][rt][2] = hv.z; acc[ct][rt][3] = hv.w; }
  }
  {
    bf16x8 waA[4], waB[4];
    LW1(waA, 0);
    G1STEP(0, waA, waB, 1)
    G1STEP(1, waB, waA, 1)
    G1STEP(2, waA, waB, 1)
    G1STEP(3, waB, waA, 1)
    G1STEP(4, waA, waB, 1)
    G1STEP(5, waB, waA, 0)
  }
  __syncthreads();   // all G1 reads of buf done

  // ---- h = silu(acc) -> buf in place (256 cols) ----
  #pragma unroll
  for (int ct = 0; ct < 4; ++ct)
    #pragma unroll
    for (int rt = 0; rt < 4; ++rt) {
      us4 u = { bfb(siluf(acc[ct][rt][0])), bfb(siluf(acc[ct][rt][1])),
                bfb(siluf(acc[ct][rt][2])), bfb(siluf(acc[ct][rt][3])) };
      *(us4*)&buf[wm * 64 + rt * 16 + lj][wn * 64 + ct * 16 + lr4] = u;
    }
  __syncthreads();

  // ---- GEMM2: 9 channel-tiles, t = it*4 + wn; wm = row half ----
  f32x4 a2[3][4];
  #pragma unroll
  for (int it = 0; it < 3; ++it) {
    const int t = it * 4 + wn;
    if (t < 9) {
      const float4 bb = *(const float4*)&b2[t * 16 + lr4];
      #pragma unroll
      for (int rt = 0; rt < 4; ++rt) { a2[it][rt][0] = bb.x; a2[it][rt][1] = bb.y; a2[it][rt][2] = bb.z; a2[it][rt][3] = bb.w; }
    }
  }
  {
    bf16x8 wbA[3], wbB[3];
    LW2(wbA, 0);
    G2STEP(0, wbA, wbB, 1)
    G2STEP(1, wbB, wbA, 1)
    G2STEP(2, wbA, wbB, 1)
    G2STEP(3, wbB, wbA, 1)
    G2STEP(4, wbA, wbB, 1)
    G2STEP(5, wbB, wbA, 1)
    G2STEP(6, wbA, wbB, 1)
    G2STEP(7, wbB, wbA, 0)
  }
  __syncthreads();   // all G2 reads of buf done -> safe to overwrite with bounce

  // ---- bounce accumulators to LDS ----
  #pragma unroll
  for (int it = 0; it < 3; ++it) {
    const int t2 = it * 4 + wn;
    if (t2 < 9) {
      if (t2 < 5) {
        #pragma unroll
        for (int rt = 0; rt < 4; ++rt) {
          us4 u = { bfb(a2[it][rt][0]), bfb(a2[it][rt][1]), bfb(a2[it][rt][2]), bfb(a2[it][rt][3]) };
          *(us4*)&score_s[wm * 64 + rt * 16 + lj][t2 * 16 + lr4] = u;
        }
      } else {
        #pragma unroll
        for (int rt = 0; rt < 4; ++rt) {
          float4 v; v.x = a2[it][rt][0]; v.y = a2[it][rt][1]; v.z = a2[it][rt][2]; v.w = a2[it][rt][3];
          *(float4*)&edge_s[wm * 64 + rt * 16 + lj][(t2 - 5) * 16 + lr4] = v;
        }
      }
    }
  }
  __syncthreads();

  // ---- coalesced global stores ----
  // scores: 80 ch x 16 k-segments (16B each) = 1280 tasks
  #pragma unroll
  for (int it = 0; it < 3; ++it) {
    const int idx = it * 512 + tid;
    if (idx < 1280) {
      const int c = idx >> 4, s = idx & 15;
      bf16x8 v;
      #pragma unroll
      for (int j = 0; j < 8; ++j) v[j] = (short)score_s[s * 8 + j][c];
      *(bf16x8*)&sct[((size_t)bq * 80 + c) * 512 + k0 + s * 8] = v;
    }
  }
  // edges: 128 rows x 16 float4 segments = 2048 tasks
  #pragma unroll
  for (int it = 0; it < 4; ++it) {
    const int idx = it * 512 + tid;
    const int row = idx >> 4, sg = idx & 15;
    *(float4*)&edge_out[((size_t)bq * 512 + k0 + row) * 64 + sg * 4] = *(const float4*)&edge_s[row][sg * 4];
  }
#undef LW1
#undef G1STEP
#undef LW2
#undef G2STEP
}

// ===================== attention + outputs (XCD-swizzled, r11 verbatim) =====================
__global__ __launch_bounds__(512) void attn_kernel(
    const __hip_bfloat16* __restrict__ sct, const int* __restrict__ adj,
    const float* __restrict__ projt, const float* __restrict__ pft,
    const float* __restrict__ eow, const float* __restrict__ iow,
    const float* __restrict__ iob, float* __restrict__ out) {
  __shared__ float eo_s[3][64];
  __shared__ float io_s[256];
  __shared__ __align__(16) float wred[8][64][20];   // wave-private io reduce scratch

  const int bq = ((blockIdx.x & 7) << 6) + (blockIdx.x >> 3);
  const int b = bq >> 8;
  const int tid = threadIdx.x, lane = tid & 63, w = tid >> 6;
  const int kb = lane * 8;

  const int4 aj0 = *(const int4*)&adj[(size_t)bq * 512 + kb];
  const int4 aj1 = *(const int4*)&adj[(size_t)bq * 512 + kb + 4];
  const unsigned int mk = (aj0.x > 0 ? 1u : 0) | (aj0.y > 0 ? 2u : 0) | (aj0.z > 0 ? 4u : 0) | (aj0.w > 0 ? 8u : 0)
                        | (aj1.x > 0 ? 16u : 0) | (aj1.y > 0 ? 32u : 0) | (aj1.z > 0 ? 64u : 0) | (aj1.w > 0 ? 128u : 0);

  // ---- Phase A: equi channels d = w*8 .. w*8+7 ----
  for (int dd = 0; dd < 8; ++dd) {
    const int d = w * 8 + dd;
    const bf16x8 s8 = *(const bf16x8*)&sct[((size_t)bq * 80 + d) * 512 + kb];
    float p[8], z = 0.f, s2 = 0.f;
    #pragma unroll
    for (int j = 0; j < 8; ++j) {
      const float e = ((mk >> j) & 1) ? __expf(b2f((unsigned short)s8[j])) : 0.f;
      p[j] = e; z += e; s2 += e * e;
    }
    float ax[3];
    #pragma unroll
    for (int x = 0; x < 3; ++x) {
      const float* pr = projt + ((size_t)(b * 3 + x) * 64 + d) * 512 + kb;
      const float4 w0 = *(const float4*)pr;
      const float4 w1v = *(const float4*)(pr + 4);
      ax[x] = p[0] * w0.x + p[1] * w0.y + p[2] * w0.z + p[3] * w0.w
            + p[4] * w1v.x + p[5] * w1v.y + p[6] * w1v.z + p[7] * w1v.w;
    }
    #pragma unroll
    for (int off = 32; off; off >>= 1) {
      z += __shfl_xor(z, off, 64); s2 += __shfl_xor(s2, off, 64);
      ax[0] += __shfl_xor(ax[0], off, 64); ax[1] += __shfl_xor(ax[1], off, 64); ax[2] += __shfl_xor(ax[2], off, 64);
    }
    if (lane == 0) {
      const float sc = sqrtf(s2) / (z * z);
      eo_s[0][d] = ax[0] * sc; eo_s[1][d] = ax[1] * sc; eo_s[2][d] = ax[2] * sc;
    }
  }

  // ---- Phase B: inv heads h = w*2 .. w*2+1 (io reduced via wave-private LDS) ----
  #pragma unroll
  for (int hh = 0; hh < 2; ++hh) {
    const int h = w * 2 + hh;
    const bf16x8 s8 = *(const bf16x8*)&sct[((size_t)bq * 80 + 64 + h) * 512 + kb];
    float p[8], z = 0.f, s2 = 0.f;
    #pragma unroll
    for (int j = 0; j < 8; ++j) {
      const float e = ((mk >> j) & 1) ? __expf(b2f((unsigned short)s8[j])) : 0.f;
      p[j] = e; z += e; s2 += e * e;
    }
    f32x4 io[4];
    #pragma unroll
    for (int d4 = 0; d4 < 4; ++d4)
      #pragma unroll
      for (int di = 0; di < 4; ++di) {
        const float* pr = pft + ((size_t)(b * 256) + h * 16 + d4 * 4 + di) * 512 + kb;
        const float4 w0 = *(const float4*)pr;
        const float4 w1v = *(const float4*)(pr + 4);
        io[d4][di] = p[0] * w0.x + p[1] * w0.y + p[2] * w0.z + p[3] * w0.w
                   + p[4] * w1v.x + p[5] * w1v.y + p[6] * w1v.z + p[7] * w1v.w;
      }
    #pragma unroll
    for (int off = 32; off; off >>= 1) { z += __shfl_xor(z, off, 64); s2 += __shfl_xor(s2, off, 64); }
    #pragma unroll
    for (int d4 = 0; d4 < 4; ++d4) {
      float4 vv; vv.x = io[d4][0]; vv.y = io[d4][1]; vv.z = io[d4][2]; vv.w = io[d4][3];
      *(float4*)&wred[w][lane][d4 * 4] = vv;
    }
    const int g = lane >> 4, dd2 = lane & 15;
    float s = 0.f;
    #pragma unroll
    for (int j = 0; j < 16; ++j) s += wred[w][g * 16 + j][dd2];
    s += __shfl_xor(s, 16, 64);
    s += __shfl_xor(s, 32, 64);
    if (lane < 16) {
      const float sc = sqrtf(s2) / (z * z);
      io_s[h * 16 + dd2] = s * sc;
    }
  }
  __syncthreads();

  if (tid < 192) {   // equi_out = eo @ equi_out_w
    const int x = tid >> 6, e = tid & 63;
    float a = 0.f;
    for (int d = 0; d < 64; ++d) a += eo_s[x][d] * eow[(size_t)d * 64 + e];
    out[(size_t)bq * 192 + x * 64 + e] = a;
  }
  if (tid < 256) {   // inv_out = io @ inv_out_w + iob
    float a = iob[tid];
    for (int k = 0; k < 256; ++k) a += io_s[k] * iow[(size_t)k * 256 + tid];
    out[98304 + (size_t)bq * 256 + tid] = a;
  }
}

// ===================== launch =====================
extern "C" void kernel_launch(void* const* d_in, const int* in_sizes, int n_in,
                              void* d_out, int out_size, void* d_ws, size_t ws_size,
                              hipStream_t stream) {
  const float* equis      = (const float*)d_in[0];
  const float* invs       = (const float*)d_in[1];
  const float* cond_equis = (const float*)d_in[2];
  const float* cond_invs  = (const float*)d_in[3];
  const float* edges      = (const float*)d_in[4];
  const int*   adj        = (const int*)d_in[5];
  const float* q_w  = (const float*)d_in[6];
  const float* q_b  = (const float*)d_in[7];
  const float* k_w  = (const float*)d_in[8];
  const float* k_b  = (const float*)d_in[9];
  const float* w1   = (const float*)d_in[10];
  const float* b1   = (const float*)d_in[11];
  const float* w2   = (const float*)d_in[12];
  const float* b2   = (const float*)d_in[13];
  const float* equi_in_w  = (const float*)d_in[14];
  const float* equi_out_w = (const float*)d_in[15];
  const float* inv_in_w   = (const float*)d_in[16];
  const float* inv_in_b   = (const float*)d_in[17];
  const float* inv_out_w  = (const float*)d_in[18];
  const float* inv_out_b  = (const float*)d_in[19];

  float* out = (float*)d_out;
  float* ws  = (float*)d_ws;
  unsigned short* w1f = (unsigned short*)ws;               // 65536 us
  unsigned short* w2f = w1f + 65536;                       // 36864 us (-> 51200 floats)
  unsigned short* kmb = (unsigned short*)(ws + 51200);     // 32768 us
  float* hq    = ws + 51200 + 65536;                       // 131072 f  [bq][256]
  float* projt = hq + 131072;                              // 196608 f  [b][x][d][512]
  float* pft   = projt + 196608;                           // 262144 f  [b][ch][512]
  __hip_bfloat16* sct = (__hip_bfloat16*)(pft + 262144);   // 512*80*512 bf16 = 41.9 MB

  prep_all<<<2585, 256, 0, stream>>>(invs, cond_invs, cond_equis,
                                     q_w, q_b, k_w, k_b, w1, b1, w2,
                                     equi_in_w, inv_in_w, inv_in_b,
                                     w1f, w2f, kmb, hq, projt, pft);

  msg_kernel<<<2048, 512, 0, stream>>>(equis, cond_equis, edges, hq, kmb,
                                       w1f, w2f, b2,
                                       out + 229376 /*edge_out*/, sct);

  attn_kernel<<<512, 512, 0, stream>>>(sct, adj, projt, pft,
                                       equi_out_w, inv_out_w, inv_out_b, out);
}

// Round 15
// 149.109 us; speedup vs baseline: 1.1767x; 1.1767x over previous
//
#include <hip/hip_runtime.h>
#include <hip/hip_bf16.h>

#define DEVINL static __device__ __forceinline__

typedef __attribute__((ext_vector_type(8))) short bf16x8;
typedef __attribute__((ext_vector_type(8))) unsigned short us8;
typedef __attribute__((ext_vector_type(4))) float f32x4;
typedef __attribute__((ext_vector_type(4))) unsigned short us4;

DEVINL float siluf(float x) { return x / (1.0f + __expf(-x)); }
DEVINL unsigned short bfb(float x) { __hip_bfloat16 h = __float2bfloat16(x); return *(unsigned short*)&h; }
DEVINL float b2f(unsigned short u) { return __uint_as_float(((unsigned int)u) << 16); }

// ===================== fused prep kernel =====================
// blocks [0,25): wfrag | [25,281): km(bf16) | [281,1049): projt | [1049,2073): pft | [2073,2585): hq
__global__ __launch_bounds__(256) void prep_all(
    const float* __restrict__ invs, const float* __restrict__ cond_invs,
    const float* __restrict__ cond_equis,
    const float* __restrict__ q_w, const float* __restrict__ q_b,
    const float* __restrict__ k_w, const float* __restrict__ k_b,
    const float* __restrict__ w1, const float* __restrict__ b1,
    const float* __restrict__ w2,
    const float* __restrict__ equi_in_w,
    const float* __restrict__ inv_in_w, const float* __restrict__ inv_in_b,
    unsigned short* __restrict__ w1f, unsigned short* __restrict__ w2f,
    unsigned short* __restrict__ kmb, float* __restrict__ hq,
    float* __restrict__ projt, float* __restrict__ pft) {
  __shared__ float smem_f[1024];
  const int blk = blockIdx.x, tid = threadIdx.x;

  if (blk < 25) {   // ---- weights to fragment order ----
    const int g = blk;
    if (g < 16) {
      #pragma unroll
      for (int e2 = 0; e2 < 16; ++e2) {
        const int flat = tid * 16 + e2;
        const int kk = flat >> 9, rem = flat & 511, ln = rem >> 3, e = rem & 7;
        const int c = g * 16 + (ln & 15);
        const int k = kk * 32 + (ln >> 4) * 8 + e;
        w1f[(size_t)g * 4096 + flat] = bfb(w1[(size_t)k * 256 + c]);
      }
    } else {
      const int t = g - 16;
      #pragma unroll
      for (int e2 = 0; e2 < 16; ++e2) {
        const int flat = tid * 16 + e2;
        const int kk = flat >> 9, rem = flat & 511, ln = rem >> 3, e = rem & 7;
        const int c = t * 16 + (ln & 15);
        const int k = kk * 32 + (ln >> 4) * 8 + e;
        w2f[(size_t)t * 4096 + flat] = bfb(w2[(size_t)k * 144 + c]);
      }
    }
    return;
  }
  if (blk < 281) {  // ---- kmb = bf16(cond_invs @ k_w + k_b) (4 rows/block) ----
    const int row = (blk - 25) * 4 + (tid >> 6), c = tid & 63;
    float* srow = smem_f + (tid >> 6) * 256;
    for (int k = c; k < 256; k += 64) srow[k] = cond_invs[(size_t)row * 256 + k];
    __syncthreads();
    float a = k_b[c];
    for (int k = 0; k < 256; ++k) a += srow[k] * k_w[(size_t)k * 64 + c];
    kmb[(size_t)row * 64 + c] = bfb(a);
    return;
  }
  if (blk < 1049) { // ---- projt (k-major), 4 rows/block ----
    const int r = (blk - 281) * 4 + (tid >> 6), c = tid & 63;
    float* srow = smem_f + (tid >> 6) * 64;
    srow[c] = cond_equis[(size_t)r * 64 + c];
    __syncthreads();
    float a = 0.f;
    for (int k = 0; k < 64; ++k) a += srow[k] * equi_in_w[(size_t)k * 64 + c];
    const int b = r / 1536, rr = r % 1536, kn = rr / 3, x = rr % 3;
    projt[((size_t)(b * 3 + x) * 64 + c) * 512 + kn] = a;
    return;
  }
  if (blk < 2073) { // ---- pft (k-major) ----
    const int r = blk - 1049, b = r >> 9, kn = r & 511;
    smem_f[tid] = cond_invs[(size_t)r * 256 + tid];
    __syncthreads();
    float a = inv_in_b[tid];
    for (int k = 0; k < 256; ++k) a += smem_f[k] * inv_in_w[(size_t)k * 256 + tid];
    pft[((size_t)(b * 256) + tid) * 512 + kn] = a;
    return;
  }
  {   // ---- hq[bq][256] = b1 + (invs@q_w + q_b) @ w1[0:64,:] ----
    const int r = blk - 2073;
    smem_f[tid] = invs[(size_t)r * 256 + tid];
    __syncthreads();
    if (tid < 64) {
      float a = q_b[tid];
      for (int k = 0; k < 256; ++k) a += smem_f[k] * q_w[(size_t)k * 64 + tid];
      smem_f[256 + tid] = a;
    }
    __syncthreads();
    float a = b1[tid];
    for (int d = 0; d < 64; ++d) a += smem_f[256 + d] * w1[(size_t)d * 256 + tid];
    hq[(size_t)r * 256 + tid] = a;
  }
}

// ===================== main message kernel (r13 + eq_s LDS dot, r8's best staging) =====================
// grid = 4096; lb = (bid&7)*512 + bid>>3 so all 8 k-tiles of a bq share one XCD.
__global__ __launch_bounds__(256, 2) void msg_kernel(
    const float* __restrict__ equis, const float* __restrict__ cond_equis,
    const float* __restrict__ edges,
    const float* __restrict__ hq, const unsigned short* __restrict__ kmb,
    const unsigned short* __restrict__ w1f,
    const unsigned short* __restrict__ w2f, const float* __restrict__ b2,
    float* __restrict__ edge_out, __hip_bfloat16* __restrict__ sct) {
  __shared__ __align__(16) unsigned short buf[64][264];   // feats -> h -> bounce (aliased)
  __shared__ float eq_s[192];
  unsigned short (*score_s)[92] = (unsigned short (*)[92])&buf[0][0];          // 11776 B
  float (*edge_s)[68]           = (float (*)[68])((char*)&buf[0][0] + 11776);  // 17408 B -> 29184 <= 33792

  const int lb = ((blockIdx.x & 7) << 9) + (blockIdx.x >> 3);   // XCD-contiguous bq groups
  const int bq = lb >> 3;             // b*256+q
  const int b  = bq >> 8;
  const int k0 = (lb & 7) * 64;
  const int tid = threadIdx.x;
  const int lane = tid & 63, wn = tid >> 6;
  const int lj  = lane & 15;
  const int lkb = (lane >> 4) * 8;
  const int lr4 = (lane >> 4) * 4;

  if (tid < 192) eq_s[tid] = equis[(size_t)bq * 192 + tid];
  __syncthreads();   // eq_s visible (only 1 load precedes -> near-free barrier)

  // ---- stage km bf16 copy (cols 0..63), edges (cols 128..191), dot (cols 64..127) ----
  #pragma unroll
  for (int it = 0; it < 2; ++it) {
    const int flat = it * 256 + tid, row = flat >> 3, seg = flat & 7;
    *(us8*)&buf[row][seg * 8] = *(const us8*)&kmb[((size_t)(b * 512 + k0 + row)) * 64 + seg * 8];
  }
  #pragma unroll
  for (int it = 0; it < 4; ++it) {
    const int flat = it * 256 + tid, row = flat >> 4, seg = flat & 15;
    const float4 v = *(const float4*)&edges[((size_t)bq * 512 + k0 + row) * 64 + seg * 4];
    us4 u = { bfb(v.x), bfb(v.y), bfb(v.z), bfb(v.w) };
    *(us4*)&buf[row][128 + seg * 4] = u;
  }
  {
    const int r = tid >> 2, dseg = tid & 3;
    const float* cer = cond_equis + ((size_t)(b * 512 + k0 + r)) * 192 + dseg * 16;
    float dv[16];
    #pragma unroll
    for (int j = 0; j < 16; ++j) dv[j] = 0.f;
    #pragma unroll
    for (int sec = 0; sec < 3; ++sec) {
      #pragma unroll
      for (int q4 = 0; q4 < 4; ++q4) {
        const float4 cv = *(const float4*)&cer[sec * 64 + q4 * 4];
        const float4 ev = *(const float4*)&eq_s[sec * 64 + dseg * 16 + q4 * 4];   // LDS (r8 pattern)
        dv[q4 * 4 + 0] += cv.x * ev.x;
        dv[q4 * 4 + 1] += cv.y * ev.y;
        dv[q4 * 4 + 2] += cv.z * ev.z;
        dv[q4 * 4 + 3] += cv.w * ev.w;
      }
    }
    us8 o0, o1;
    #pragma unroll
    for (int j = 0; j < 8; ++j) { o0[j] = bfb(dv[j]); o1[j] = bfb(dv[8 + j]); }
    *(us8*)&buf[r][64 + dseg * 16] = o0;
    *(us8*)&buf[r][64 + dseg * 16 + 8] = o1;
  }
  __syncthreads();

// weight fragments: GEMM1 uses w1 rows 64..255 -> w1f kk index (KK+2)
#define LW1(BUF, KK) { \
    _Pragma("unroll") for (int ct = 0; ct < 4; ++ct) \
      BUF[ct] = *(const bf16x8*)&w1f[((size_t)(((wn * 4 + ct) * 8 + ((KK) + 2)) * 64) + lane) * 8]; }

#define G1STEP(KK, CUR, NXT, DOPF) { \
    if (DOPF) { LW1(NXT, (KK) + 1); } \
    bf16x8 fbv[4]; \
    _Pragma("unroll") for (int rt = 0; rt < 4; ++rt) \
      fbv[rt] = *(const bf16x8*)&buf[rt * 16 + lj][(KK) * 32 + lkb]; \
    _Pragma("unroll") for (int ct = 0; ct < 4; ++ct) \
      _Pragma("unroll") for (int rt = 0; rt < 4; ++rt) \
        acc[ct][rt] = __builtin_amdgcn_mfma_f32_16x16x32_bf16(CUR[ct], fbv[rt], acc[ct][rt], 0, 0, 0); }

#define LW2(BUF, KK) { \
    _Pragma("unroll") for (int it = 0; it < 3; ++it) { \
      const int t = it * 4 + wn; \
      if (t < 9) BUF[it] = *(const bf16x8*)&w2f[((size_t)((t * 8 + (KK)) * 64) + lane) * 8]; } }

#define G2STEP(KK, CUR, NXT, DOPF) { \
    if (DOPF) { LW2(NXT, (KK) + 1); } \
    bf16x8 fbv[4]; \
    _Pragma("unroll") for (int rt = 0; rt < 4; ++rt) \
      fbv[rt] = *(const bf16x8*)&buf[rt * 16 + lj][(KK) * 32 + lkb]; \
    _Pragma("unroll") for (int it = 0; it < 3; ++it) { \
      const int t = it * 4 + wn; \
      if (t < 9) { \
        _Pragma("unroll") for (int rt = 0; rt < 4; ++rt) \
          a2[it][rt] = __builtin_amdgcn_mfma_f32_16x16x32_bf16(CUR[it], fbv[rt], a2[it][rt], 0, 0, 0); \
      } } }

  // ---- GEMM1: acc init from hq (qm contribution + b1), 6 kk steps over buf ----
  f32x4 acc[4][4];
  #pragma unroll
  for (int ct = 0; ct < 4; ++ct) {
    const float4 hv = *(const float4*)&hq[(size_t)bq * 256 + wn * 64 + ct * 16 + lr4];
    #pragma unroll
    for (int rt = 0; rt < 4; ++rt) { acc[ct][rt][0] = hv.x; acc[ct][rt][1] = hv.y; acc[ct][rt][2] = hv.z; acc[ct][rt][3] = hv.w; }
  }
  {
    bf16x8 waA[4], waB[4];
    LW1(waA, 0);
    G1STEP(0, waA, waB, 1)
    G1STEP(1, waB, waA, 1)
    G1STEP(2, waA, waB, 1)
    G1STEP(3, waB, waA, 1)
    G1STEP(4, waA, waB, 1)
    G1STEP(5, waB, waA, 0)
  }
  __syncthreads();   // all G1 reads of buf done

  // ---- h = silu(acc) -> buf in place (256 cols) ----
  #pragma unroll
  for (int ct = 0; ct < 4; ++ct)
    #pragma unroll
    for (int rt = 0; rt < 4; ++rt) {
      us4 u = { bfb(siluf(acc[ct][rt][0])), bfb(siluf(acc[ct][rt][1])),
                bfb(siluf(acc[ct][rt][2])), bfb(siluf(acc[ct][rt][3])) };
      *(us4*)&buf[rt * 16 + lj][wn * 64 + ct * 16 + lr4] = u;
    }
  __syncthreads();

  // ---- GEMM2: 9 channel-tiles, t = it*4 + wn ----
  f32x4 a2[3][4];
  #pragma unroll
  for (int it = 0; it < 3; ++it) {
    const int t = it * 4 + wn;
    if (t < 9) {
      const float4 bb = *(const float4*)&b2[t * 16 + lr4];
      #pragma unroll
      for (int rt = 0; rt < 4; ++rt) { a2[it][rt][0] = bb.x; a2[it][rt][1] = bb.y; a2[it][rt][2] = bb.z; a2[it][rt][3] = bb.w; }
    }
  }
  {
    bf16x8 wbA[3], wbB[3];
    LW2(wbA, 0);
    G2STEP(0, wbA, wbB, 1)
    G2STEP(1, wbB, wbA, 1)
    G2STEP(2, wbA, wbB, 1)
    G2STEP(3, wbB, wbA, 1)
    G2STEP(4, wbA, wbB, 1)
    G2STEP(5, wbB, wbA, 1)
    G2STEP(6, wbA, wbB, 1)
    G2STEP(7, wbB, wbA, 0)
  }
  __syncthreads();   // all G2 reads of buf done -> safe to overwrite with bounce

  // ---- bounce accumulators to LDS ----
  #pragma unroll
  for (int it = 0; it < 3; ++it) {
    const int t2 = it * 4 + wn;
    if (t2 < 9) {
      if (t2 < 5) {
        #pragma unroll
        for (int rt = 0; rt < 4; ++rt) {
          us4 u = { bfb(a2[it][rt][0]), bfb(a2[it][rt][1]), bfb(a2[it][rt][2]), bfb(a2[it][rt][3]) };
          *(us4*)&score_s[rt * 16 + lj][t2 * 16 + lr4] = u;
        }
      } else {
        #pragma unroll
        for (int rt = 0; rt < 4; ++rt) {
          float4 v; v.x = a2[it][rt][0]; v.y = a2[it][rt][1]; v.z = a2[it][rt][2]; v.w = a2[it][rt][3];
          *(float4*)&edge_s[rt * 16 + lj][(t2 - 5) * 16 + lr4] = v;
        }
      }
    }
  }
  __syncthreads();

  // ---- coalesced global stores ----
  #pragma unroll
  for (int it = 0; it < 3; ++it) {
    const int idx = it * 256 + tid;
    if (idx < 640) {
      const int c = idx >> 3, s = idx & 7;
      bf16x8 v;
      #pragma unroll
      for (int j = 0; j < 8; ++j) v[j] = (short)score_s[s * 8 + j][c];
      *(bf16x8*)&sct[((size_t)bq * 80 + c) * 512 + k0 + s * 8] = v;
    }
  }
  #pragma unroll
  for (int it = 0; it < 4; ++it) {
    const int idx = it * 256 + tid;
    const int row = idx >> 4, sg = idx & 15;
    *(float4*)&edge_out[((size_t)bq * 512 + k0 + row) * 64 + sg * 4] = *(const float4*)&edge_s[row][sg * 4];
  }
#undef LW1
#undef G1STEP
#undef LW2
#undef G2STEP
}

// ===================== attention + outputs (XCD-swizzled, r11 verbatim) =====================
__global__ __launch_bounds__(512) void attn_kernel(
    const __hip_bfloat16* __restrict__ sct, const int* __restrict__ adj,
    const float* __restrict__ projt, const float* __restrict__ pft,
    const float* __restrict__ eow, const float* __restrict__ iow,
    const float* __restrict__ iob, float* __restrict__ out) {
  __shared__ float eo_s[3][64];
  __shared__ float io_s[256];
  __shared__ __align__(16) float wred[8][64][20];   // wave-private io reduce scratch

  const int bq = ((blockIdx.x & 7) << 6) + (blockIdx.x >> 3);
  const int b = bq >> 8;
  const int tid = threadIdx.x, lane = tid & 63, w = tid >> 6;
  const int kb = lane * 8;

  const int4 aj0 = *(const int4*)&adj[(size_t)bq * 512 + kb];
  const int4 aj1 = *(const int4*)&adj[(size_t)bq * 512 + kb + 4];
  const unsigned int mk = (aj0.x > 0 ? 1u : 0) | (aj0.y > 0 ? 2u : 0) | (aj0.z > 0 ? 4u : 0) | (aj0.w > 0 ? 8u : 0)
                        | (aj1.x > 0 ? 16u : 0) | (aj1.y > 0 ? 32u : 0) | (aj1.z > 0 ? 64u : 0) | (aj1.w > 0 ? 128u : 0);

  // ---- Phase A: equi channels d = w*8 .. w*8+7 ----
  for (int dd = 0; dd < 8; ++dd) {
    const int d = w * 8 + dd;
    const bf16x8 s8 = *(const bf16x8*)&sct[((size_t)bq * 80 + d) * 512 + kb];
    float p[8], z = 0.f, s2 = 0.f;
    #pragma unroll
    for (int j = 0; j < 8; ++j) {
      const float e = ((mk >> j) & 1) ? __expf(b2f((unsigned short)s8[j])) : 0.f;
      p[j] = e; z += e; s2 += e * e;
    }
    float ax[3];
    #pragma unroll
    for (int x = 0; x < 3; ++x) {
      const float* pr = projt + ((size_t)(b * 3 + x) * 64 + d) * 512 + kb;
      const float4 w0 = *(const float4*)pr;
      const float4 w1v = *(const float4*)(pr + 4);
      ax[x] = p[0] * w0.x + p[1] * w0.y + p[2] * w0.z + p[3] * w0.w
            + p[4] * w1v.x + p[5] * w1v.y + p[6] * w1v.z + p[7] * w1v.w;
    }
    #pragma unroll
    for (int off = 32; off; off >>= 1) {
      z += __shfl_xor(z, off, 64); s2 += __shfl_xor(s2, off, 64);
      ax[0] += __shfl_xor(ax[0], off, 64); ax[1] += __shfl_xor(ax[1], off, 64); ax[2] += __shfl_xor(ax[2], off, 64);
    }
    if (lane == 0) {
      const float sc = sqrtf(s2) / (z * z);
      eo_s[0][d] = ax[0] * sc; eo_s[1][d] = ax[1] * sc; eo_s[2][d] = ax[2] * sc;
    }
  }

  // ---- Phase B: inv heads h = w*2 .. w*2+1 (io reduced via wave-private LDS) ----
  #pragma unroll
  for (int hh = 0; hh < 2; ++hh) {
    const int h = w * 2 + hh;
    const bf16x8 s8 = *(const bf16x8*)&sct[((size_t)bq * 80 + 64 + h) * 512 + kb];
    float p[8], z = 0.f, s2 = 0.f;
    #pragma unroll
    for (int j = 0; j < 8; ++j) {
      const float e = ((mk >> j) & 1) ? __expf(b2f((unsigned short)s8[j])) : 0.f;
      p[j] = e; z += e; s2 += e * e;
    }
    f32x4 io[4];
    #pragma unroll
    for (int d4 = 0; d4 < 4; ++d4)
      #pragma unroll
      for (int di = 0; di < 4; ++di) {
        const float* pr = pft + ((size_t)(b * 256) + h * 16 + d4 * 4 + di) * 512 + kb;
        const float4 w0 = *(const float4*)pr;
        const float4 w1v = *(const float4*)(pr + 4);
        io[d4][di] = p[0] * w0.x + p[1] * w0.y + p[2] * w0.z + p[3] * w0.w
                   + p[4] * w1v.x + p[5] * w1v.y + p[6] * w1v.z + p[7] * w1v.w;
      }
    #pragma unroll
    for (int off = 32; off; off >>= 1) { z += __shfl_xor(z, off, 64); s2 += __shfl_xor(s2, off, 64); }
    #pragma unroll
    for (int d4 = 0; d4 < 4; ++d4) {
      float4 vv; vv.x = io[d4][0]; vv.y = io[d4][1]; vv.z = io[d4][2]; vv.w = io[d4][3];
      *(float4*)&wred[w][lane][d4 * 4] = vv;
    }
    const int g = lane >> 4, dd2 = lane & 15;
    float s = 0.f;
    #pragma unroll
    for (int j = 0; j < 16; ++j) s += wred[w][g * 16 + j][dd2];
    s += __shfl_xor(s, 16, 64);
    s += __shfl_xor(s, 32, 64);
    if (lane < 16) {
      const float sc = sqrtf(s2) / (z * z);
      io_s[h * 16 + dd2] = s * sc;
    }
  }
  __syncthreads();

  if (tid < 192) {   // equi_out = eo @ equi_out_w
    const int x = tid >> 6, e = tid & 63;
    float a = 0.f;
    for (int d = 0; d < 64; ++d) a += eo_s[x][d] * eow[(size_t)d * 64 + e];
    out[(size_t)bq * 192 + x * 64 + e] = a;
  }
  if (tid < 256) {   // inv_out = io @ inv_out_w + iob
    float a = iob[tid];
    for (int k = 0; k < 256; ++k) a += io_s[k] * iow[(size_t)k * 256 + tid];
    out[98304 + (size_t)bq * 256 + tid] = a;
  }
}

// ===================== launch =====================
extern "C" void kernel_launch(void* const* d_in, const int* in_sizes, int n_in,
                              void* d_out, int out_size, void* d_ws, size_t ws_size,
                              hipStream_t stream) {
  const float* equis      = (const float*)d_in[0];
  const float* invs       = (const float*)d_in[1];
  const float* cond_equis = (const float*)d_in[2];
  const float* cond_invs  = (const float*)d_in[3];
  const float* edges      = (const float*)d_in[4];
  const int*   adj        = (const int*)d_in[5];
  const float* q_w  = (const float*)d_in[6];
  const float* q_b  = (const float*)d_in[7];
  const float* k_w  = (const float*)d_in[8];
  const float* k_b  = (const float*)d_in[9];
  const float* w1   = (const float*)d_in[10];
  const float* b1   = (const float*)d_in[11];
  const float* w2   = (const float*)d_in[12];
  const float* b2   = (const float*)d_in[13];
  const float* equi_in_w  = (const float*)d_in[14];
  const float* equi_out_w = (const float*)d_in[15];
  const float* inv_in_w   = (const float*)d_in[16];
  const float* inv_in_b   = (const float*)d_in[17];
  const float* inv_out_w  = (const float*)d_in[18];
  const float* inv_out_b  = (const float*)d_in[19];

  float* out = (float*)d_out;
  float* ws  = (float*)d_ws;
  unsigned short* w1f = (unsigned short*)ws;               // 65536 us
  unsigned short* w2f = w1f + 65536;                       // 36864 us (-> 51200 floats)
  unsigned short* kmb = (unsigned short*)(ws + 51200);     // 32768 us
  float* hq    = ws + 51200 + 65536;                       // 131072 f  [bq][256]
  float* projt = hq + 131072;                              // 196608 f  [b][x][d][512]
  float* pft   = projt + 196608;                           // 262144 f  [b][ch][512]
  __hip_bfloat16* sct = (__hip_bfloat16*)(pft + 262144);   // 512*80*512 bf16 = 41.9 MB

  prep_all<<<2585, 256, 0, stream>>>(invs, cond_invs, cond_equis,
                                     q_w, q_b, k_w, k_b, w1, b1, w2,
                                     equi_in_w, inv_in_w, inv_in_b,
                                     w1f, w2f, kmb, hq, projt, pft);

  msg_kernel<<<4096, 256, 0, stream>>>(equis, cond_equis, edges, hq, kmb,
                                       w1f, w2f, b2,
                                       out + 229376 /*edge_out*/, sct);

  attn_kernel<<<512, 512, 0, stream>>>(sct, adj, projt, pft,
                                       equi_out_w, inv_out_w, inv_out_b, out);
}

// Round 16
// 148.476 us; speedup vs baseline: 1.1817x; 1.0043x over previous
//
#include <hip/hip_runtime.h>
#include <hip/hip_bf16.h>

#define DEVINL static __device__ __forceinline__

typedef __attribute__((ext_vector_type(8))) short bf16x8;
typedef __attribute__((ext_vector_type(8))) unsigned short us8;
typedef __attribute__((ext_vector_type(4))) float f32x4;
typedef __attribute__((ext_vector_type(4))) unsigned short us4;

DEVINL float siluf(float x) { return x / (1.0f + __expf(-x)); }
DEVINL unsigned short bfb(float x) { __hip_bfloat16 h = __float2bfloat16(x); return *(unsigned short*)&h; }
DEVINL float b2f(unsigned short u) { return __uint_as_float(((unsigned int)u) << 16); }

// ===================== fused prep kernel =====================
// blocks [0,25): wfrag | [25,281): km(bf16) | [281,1049): projt | [1049,2073): pft | [2073,2585): hq
__global__ __launch_bounds__(256) void prep_all(
    const float* __restrict__ invs, const float* __restrict__ cond_invs,
    const float* __restrict__ cond_equis,
    const float* __restrict__ q_w, const float* __restrict__ q_b,
    const float* __restrict__ k_w, const float* __restrict__ k_b,
    const float* __restrict__ w1, const float* __restrict__ b1,
    const float* __restrict__ w2,
    const float* __restrict__ equi_in_w,
    const float* __restrict__ inv_in_w, const float* __restrict__ inv_in_b,
    unsigned short* __restrict__ w1f, unsigned short* __restrict__ w2f,
    unsigned short* __restrict__ kmb, float* __restrict__ hq,
    float* __restrict__ projt, float* __restrict__ pft) {
  __shared__ float smem_f[1024];
  const int blk = blockIdx.x, tid = threadIdx.x;

  if (blk < 25) {   // ---- weights to fragment order ----
    const int g = blk;
    if (g < 16) {
      #pragma unroll
      for (int e2 = 0; e2 < 16; ++e2) {
        const int flat = tid * 16 + e2;
        const int kk = flat >> 9, rem = flat & 511, ln = rem >> 3, e = rem & 7;
        const int c = g * 16 + (ln & 15);
        const int k = kk * 32 + (ln >> 4) * 8 + e;
        w1f[(size_t)g * 4096 + flat] = bfb(w1[(size_t)k * 256 + c]);
      }
    } else {
      const int t = g - 16;
      #pragma unroll
      for (int e2 = 0; e2 < 16; ++e2) {
        const int flat = tid * 16 + e2;
        const int kk = flat >> 9, rem = flat & 511, ln = rem >> 3, e = rem & 7;
        const int c = t * 16 + (ln & 15);
        const int k = kk * 32 + (ln >> 4) * 8 + e;
        w2f[(size_t)t * 4096 + flat] = bfb(w2[(size_t)k * 144 + c]);
      }
    }
    return;
  }
  if (blk < 281) {  // ---- kmb = bf16(cond_invs @ k_w + k_b) (4 rows/block) ----
    const int row = (blk - 25) * 4 + (tid >> 6), c = tid & 63;
    float* srow = smem_f + (tid >> 6) * 256;
    for (int k = c; k < 256; k += 64) srow[k] = cond_invs[(size_t)row * 256 + k];
    __syncthreads();
    float a = k_b[c];
    for (int k = 0; k < 256; ++k) a += srow[k] * k_w[(size_t)k * 64 + c];
    kmb[(size_t)row * 64 + c] = bfb(a);
    return;
  }
  if (blk < 1049) { // ---- projt (k-major), 4 rows/block ----
    const int r = (blk - 281) * 4 + (tid >> 6), c = tid & 63;
    float* srow = smem_f + (tid >> 6) * 64;
    srow[c] = cond_equis[(size_t)r * 64 + c];
    __syncthreads();
    float a = 0.f;
    for (int k = 0; k < 64; ++k) a += srow[k] * equi_in_w[(size_t)k * 64 + c];
    const int b = r / 1536, rr = r % 1536, kn = rr / 3, x = rr % 3;
    projt[((size_t)(b * 3 + x) * 64 + c) * 512 + kn] = a;
    return;
  }
  if (blk < 2073) { // ---- pft (k-major) ----
    const int r = blk - 1049, b = r >> 9, kn = r & 511;
    smem_f[tid] = cond_invs[(size_t)r * 256 + tid];
    __syncthreads();
    float a = inv_in_b[tid];
    for (int k = 0; k < 256; ++k) a += smem_f[k] * inv_in_w[(size_t)k * 256 + tid];
    pft[((size_t)(b * 256) + tid) * 512 + kn] = a;
    return;
  }
  {   // ---- hq[bq][256] = b1 + (invs@q_w + q_b) @ w1[0:64,:] ----
    const int r = blk - 2073;
    smem_f[tid] = invs[(size_t)r * 256 + tid];
    __syncthreads();
    if (tid < 64) {
      float a = q_b[tid];
      for (int k = 0; k < 256; ++k) a += smem_f[k] * q_w[(size_t)k * 64 + tid];
      smem_f[256 + tid] = a;
    }
    __syncthreads();
    float a = b1[tid];
    for (int d = 0; d < 64; ++d) a += smem_f[256 + d] * w1[(size_t)d * 256 + tid];
    hq[(size_t)r * 256 + tid] = a;
  }
}

// score-bounce LDS addressing: 64 rows x 256B slots, XOR-swizzled (bits 4-6 by (row&7)^(row>>3))
#define SOFF(row, cus) ((((row) << 8) + ((cus) << 1)) ^ (((((row) & 7) ^ (((row) >> 3) & 7))) << 4))

// ===================== main message kernel (r15 + XOR-swizzled score bounce) =====================
// grid = 4096; lb = (bid&7)*512 + bid>>3 so all 8 k-tiles of a bq share one XCD.
__global__ __launch_bounds__(256, 2) void msg_kernel(
    const float* __restrict__ equis, const float* __restrict__ cond_equis,
    const float* __restrict__ edges,
    const float* __restrict__ hq, const unsigned short* __restrict__ kmb,
    const unsigned short* __restrict__ w1f,
    const unsigned short* __restrict__ w2f, const float* __restrict__ b2,
    float* __restrict__ edge_out, __hip_bfloat16* __restrict__ sct) {
  __shared__ __align__(16) unsigned short buf[64][264];   // feats -> h -> bounce (aliased)
  __shared__ float eq_s[192];
  unsigned char* const sbase = (unsigned char*)&buf[0][0];                     // score area: 64*256 = 16384 B
  float (*edge_s)[68] = (float (*)[68])((char*)&buf[0][0] + 16384);            // 17408 B -> 33792 total (exact)

  const int lb = ((blockIdx.x & 7) << 9) + (blockIdx.x >> 3);   // XCD-contiguous bq groups
  const int bq = lb >> 3;             // b*256+q
  const int b  = bq >> 8;
  const int k0 = (lb & 7) * 64;
  const int tid = threadIdx.x;
  const int lane = tid & 63, wn = tid >> 6;
  const int lj  = lane & 15;
  const int lkb = (lane >> 4) * 8;
  const int lr4 = (lane >> 4) * 4;

  if (tid < 192) eq_s[tid] = equis[(size_t)bq * 192 + tid];
  __syncthreads();   // eq_s visible (only 1 load precedes -> near-free barrier)

  // ---- stage km bf16 copy (cols 0..63), edges (cols 128..191), dot (cols 64..127) ----
  #pragma unroll
  for (int it = 0; it < 2; ++it) {
    const int flat = it * 256 + tid, row = flat >> 3, seg = flat & 7;
    *(us8*)&buf[row][seg * 8] = *(const us8*)&kmb[((size_t)(b * 512 + k0 + row)) * 64 + seg * 8];
  }
  #pragma unroll
  for (int it = 0; it < 4; ++it) {
    const int flat = it * 256 + tid, row = flat >> 4, seg = flat & 15;
    const float4 v = *(const float4*)&edges[((size_t)bq * 512 + k0 + row) * 64 + seg * 4];
    us4 u = { bfb(v.x), bfb(v.y), bfb(v.z), bfb(v.w) };
    *(us4*)&buf[row][128 + seg * 4] = u;
  }
  {
    const int r = tid >> 2, dseg = tid & 3;
    const float* cer = cond_equis + ((size_t)(b * 512 + k0 + r)) * 192 + dseg * 16;
    float dv[16];
    #pragma unroll
    for (int j = 0; j < 16; ++j) dv[j] = 0.f;
    #pragma unroll
    for (int sec = 0; sec < 3; ++sec) {
      #pragma unroll
      for (int q4 = 0; q4 < 4; ++q4) {
        const float4 cv = *(const float4*)&cer[sec * 64 + q4 * 4];
        const float4 ev = *(const float4*)&eq_s[sec * 64 + dseg * 16 + q4 * 4];   // LDS (r8 pattern)
        dv[q4 * 4 + 0] += cv.x * ev.x;
        dv[q4 * 4 + 1] += cv.y * ev.y;
        dv[q4 * 4 + 2] += cv.z * ev.z;
        dv[q4 * 4 + 3] += cv.w * ev.w;
      }
    }
    us8 o0, o1;
    #pragma unroll
    for (int j = 0; j < 8; ++j) { o0[j] = bfb(dv[j]); o1[j] = bfb(dv[8 + j]); }
    *(us8*)&buf[r][64 + dseg * 16] = o0;
    *(us8*)&buf[r][64 + dseg * 16 + 8] = o1;
  }
  __syncthreads();

// weight fragments: GEMM1 uses w1 rows 64..255 -> w1f kk index (KK+2)
#define LW1(BUF, KK) { \
    _Pragma("unroll") for (int ct = 0; ct < 4; ++ct) \
      BUF[ct] = *(const bf16x8*)&w1f[((size_t)(((wn * 4 + ct) * 8 + ((KK) + 2)) * 64) + lane) * 8]; }

#define G1STEP(KK, CUR, NXT, DOPF) { \
    if (DOPF) { LW1(NXT, (KK) + 1); } \
    bf16x8 fbv[4]; \
    _Pragma("unroll") for (int rt = 0; rt < 4; ++rt) \
      fbv[rt] = *(const bf16x8*)&buf[rt * 16 + lj][(KK) * 32 + lkb]; \
    _Pragma("unroll") for (int ct = 0; ct < 4; ++ct) \
      _Pragma("unroll") for (int rt = 0; rt < 4; ++rt) \
        acc[ct][rt] = __builtin_amdgcn_mfma_f32_16x16x32_bf16(CUR[ct], fbv[rt], acc[ct][rt], 0, 0, 0); }

#define LW2(BUF, KK) { \
    _Pragma("unroll") for (int it = 0; it < 3; ++it) { \
      const int t = it * 4 + wn; \
      if (t < 9) BUF[it] = *(const bf16x8*)&w2f[((size_t)((t * 8 + (KK)) * 64) + lane) * 8]; } }

#define G2STEP(KK, CUR, NXT, DOPF) { \
    if (DOPF) { LW2(NXT, (KK) + 1); } \
    bf16x8 fbv[4]; \
    _Pragma("unroll") for (int rt = 0; rt < 4; ++rt) \
      fbv[rt] = *(const bf16x8*)&buf[rt * 16 + lj][(KK) * 32 + lkb]; \
    _Pragma("unroll") for (int it = 0; it < 3; ++it) { \
      const int t = it * 4 + wn; \
      if (t < 9) { \
        _Pragma("unroll") for (int rt = 0; rt < 4; ++rt) \
          a2[it][rt] = __builtin_amdgcn_mfma_f32_16x16x32_bf16(CUR[it], fbv[rt], a2[it][rt], 0, 0, 0); \
      } } }

  // ---- GEMM1: acc init from hq (qm contribution + b1), 6 kk steps over buf ----
  f32x4 acc[4][4];
  #pragma unroll
  for (int ct = 0; ct < 4; ++ct) {
    const float4 hv = *(const float4*)&hq[(size_t)bq * 256 + wn * 64 + ct * 16 + lr4];
    #pragma unroll
    for (int rt = 0; rt < 4; ++rt) { acc[ct][rt][0] = hv.x; acc[ct][rt][1] = hv.y; acc[ct][rt][2] = hv.z; acc[ct][rt][3] = hv.w; }
  }
  {
    bf16x8 waA[4], waB[4];
    LW1(waA, 0);
    G1STEP(0, waA, waB, 1)
    G1STEP(1, waB, waA, 1)
    G1STEP(2, waA, waB, 1)
    G1STEP(3, waB, waA, 1)
    G1STEP(4, waA, waB, 1)
    G1STEP(5, waB, waA, 0)
  }
  __syncthreads();   // all G1 reads of buf done

  // ---- h = silu(acc) -> buf in place (256 cols) ----
  #pragma unroll
  for (int ct = 0; ct < 4; ++ct)
    #pragma unroll
    for (int rt = 0; rt < 4; ++rt) {
      us4 u = { bfb(siluf(acc[ct][rt][0])), bfb(siluf(acc[ct][rt][1])),
                bfb(siluf(acc[ct][rt][2])), bfb(siluf(acc[ct][rt][3])) };
      *(us4*)&buf[rt * 16 + lj][wn * 64 + ct * 16 + lr4] = u;
    }
  __syncthreads();

  // ---- GEMM2: 9 channel-tiles, t = it*4 + wn ----
  f32x4 a2[3][4];
  #pragma unroll
  for (int it = 0; it < 3; ++it) {
    const int t = it * 4 + wn;
    if (t < 9) {
      const float4 bb = *(const float4*)&b2[t * 16 + lr4];
      #pragma unroll
      for (int rt = 0; rt < 4; ++rt) { a2[it][rt][0] = bb.x; a2[it][rt][1] = bb.y; a2[it][rt][2] = bb.z; a2[it][rt][3] = bb.w; }
    }
  }
  {
    bf16x8 wbA[3], wbB[3];
    LW2(wbA, 0);
    G2STEP(0, wbA, wbB, 1)
    G2STEP(1, wbB, wbA, 1)
    G2STEP(2, wbA, wbB, 1)
    G2STEP(3, wbB, wbA, 1)
    G2STEP(4, wbA, wbB, 1)
    G2STEP(5, wbB, wbA, 1)
    G2STEP(6, wbA, wbB, 1)
    G2STEP(7, wbB, wbA, 0)
  }
  __syncthreads();   // all G2 reads of buf done -> safe to overwrite with bounce

  // ---- bounce accumulators to LDS (scores XOR-swizzled, edges linear) ----
  #pragma unroll
  for (int it = 0; it < 3; ++it) {
    const int t2 = it * 4 + wn;
    if (t2 < 9) {
      if (t2 < 5) {
        #pragma unroll
        for (int rt = 0; rt < 4; ++rt) {
          us4 u = { bfb(a2[it][rt][0]), bfb(a2[it][rt][1]), bfb(a2[it][rt][2]), bfb(a2[it][rt][3]) };
          *(us4*)(sbase + SOFF(rt * 16 + lj, t2 * 16 + lr4)) = u;
        }
      } else {
        #pragma unroll
        for (int rt = 0; rt < 4; ++rt) {
          float4 v; v.x = a2[it][rt][0]; v.y = a2[it][rt][1]; v.z = a2[it][rt][2]; v.w = a2[it][rt][3];
          *(float4*)&edge_s[rt * 16 + lj][(t2 - 5) * 16 + lr4] = v;
        }
      }
    }
  }
  __syncthreads();

  // ---- coalesced global stores ----
  #pragma unroll
  for (int it = 0; it < 3; ++it) {
    const int idx = it * 256 + tid;
    if (idx < 640) {
      const int c = idx >> 3, s = idx & 7;
      bf16x8 v;
      #pragma unroll
      for (int j = 0; j < 8; ++j)
        v[j] = *(const short*)(sbase + SOFF(s * 8 + j, c));
      *(bf16x8*)&sct[((size_t)bq * 80 + c) * 512 + k0 + s * 8] = v;
    }
  }
  #pragma unroll
  for (int it = 0; it < 4; ++it) {
    const int idx = it * 256 + tid;
    const int row = idx >> 4, sg = idx & 15;
    *(float4*)&edge_out[((size_t)bq * 512 + k0 + row) * 64 + sg * 4] = *(const float4*)&edge_s[row][sg * 4];
  }
#undef LW1
#undef G1STEP
#undef LW2
#undef G2STEP
}

// ===================== attention + outputs (XCD-swizzled, r11 verbatim) =====================
__global__ __launch_bounds__(512) void attn_kernel(
    const __hip_bfloat16* __restrict__ sct, const int* __restrict__ adj,
    const float* __restrict__ projt, const float* __restrict__ pft,
    const float* __restrict__ eow, const float* __restrict__ iow,
    const float* __restrict__ iob, float* __restrict__ out) {
  __shared__ float eo_s[3][64];
  __shared__ float io_s[256];
  __shared__ __align__(16) float wred[8][64][20];   // wave-private io reduce scratch

  const int bq = ((blockIdx.x & 7) << 6) + (blockIdx.x >> 3);
  const int b = bq >> 8;
  const int tid = threadIdx.x, lane = tid & 63, w = tid >> 6;
  const int kb = lane * 8;

  const int4 aj0 = *(const int4*)&adj[(size_t)bq * 512 + kb];
  const int4 aj1 = *(const int4*)&adj[(size_t)bq * 512 + kb + 4];
  const unsigned int mk = (aj0.x > 0 ? 1u : 0) | (aj0.y > 0 ? 2u : 0) | (aj0.z > 0 ? 4u : 0) | (aj0.w > 0 ? 8u : 0)
                        | (aj1.x > 0 ? 16u : 0) | (aj1.y > 0 ? 32u : 0) | (aj1.z > 0 ? 64u : 0) | (aj1.w > 0 ? 128u : 0);

  // ---- Phase A: equi channels d = w*8 .. w*8+7 ----
  for (int dd = 0; dd < 8; ++dd) {
    const int d = w * 8 + dd;
    const bf16x8 s8 = *(const bf16x8*)&sct[((size_t)bq * 80 + d) * 512 + kb];
    float p[8], z = 0.f, s2 = 0.f;
    #pragma unroll
    for (int j = 0; j < 8; ++j) {
      const float e = ((mk >> j) & 1) ? __expf(b2f((unsigned short)s8[j])) : 0.f;
      p[j] = e; z += e; s2 += e * e;
    }
    float ax[3];
    #pragma unroll
    for (int x = 0; x < 3; ++x) {
      const float* pr = projt + ((size_t)(b * 3 + x) * 64 + d) * 512 + kb;
      const float4 w0 = *(const float4*)pr;
      const float4 w1v = *(const float4*)(pr + 4);
      ax[x] = p[0] * w0.x + p[1] * w0.y + p[2] * w0.z + p[3] * w0.w
            + p[4] * w1v.x + p[5] * w1v.y + p[6] * w1v.z + p[7] * w1v.w;
    }
    #pragma unroll
    for (int off = 32; off; off >>= 1) {
      z += __shfl_xor(z, off, 64); s2 += __shfl_xor(s2, off, 64);
      ax[0] += __shfl_xor(ax[0], off, 64); ax[1] += __shfl_xor(ax[1], off, 64); ax[2] += __shfl_xor(ax[2], off, 64);
    }
    if (lane == 0) {
      const float sc = sqrtf(s2) / (z * z);
      eo_s[0][d] = ax[0] * sc; eo_s[1][d] = ax[1] * sc; eo_s[2][d] = ax[2] * sc;
    }
  }

  // ---- Phase B: inv heads h = w*2 .. w*2+1 (io reduced via wave-private LDS) ----
  #pragma unroll
  for (int hh = 0; hh < 2; ++hh) {
    const int h = w * 2 + hh;
    const bf16x8 s8 = *(const bf16x8*)&sct[((size_t)bq * 80 + 64 + h) * 512 + kb];
    float p[8], z = 0.f, s2 = 0.f;
    #pragma unroll
    for (int j = 0; j < 8; ++j) {
      const float e = ((mk >> j) & 1) ? __expf(b2f((unsigned short)s8[j])) : 0.f;
      p[j] = e; z += e; s2 += e * e;
    }
    f32x4 io[4];
    #pragma unroll
    for (int d4 = 0; d4 < 4; ++d4)
      #pragma unroll
      for (int di = 0; di < 4; ++di) {
        const float* pr = pft + ((size_t)(b * 256) + h * 16 + d4 * 4 + di) * 512 + kb;
        const float4 w0 = *(const float4*)pr;
        const float4 w1v = *(const float4*)(pr + 4);
        io[d4][di] = p[0] * w0.x + p[1] * w0.y + p[2] * w0.z + p[3] * w0.w
                   + p[4] * w1v.x + p[5] * w1v.y + p[6] * w1v.z + p[7] * w1v.w;
      }
    #pragma unroll
    for (int off = 32; off; off >>= 1) { z += __shfl_xor(z, off, 64); s2 += __shfl_xor(s2, off, 64); }
    #pragma unroll
    for (int d4 = 0; d4 < 4; ++d4) {
      float4 vv; vv.x = io[d4][0]; vv.y = io[d4][1]; vv.z = io[d4][2]; vv.w = io[d4][3];
      *(float4*)&wred[w][lane][d4 * 4] = vv;
    }
    const int g = lane >> 4, dd2 = lane & 15;
    float s = 0.f;
    #pragma unroll
    for (int j = 0; j < 16; ++j) s += wred[w][g * 16 + j][dd2];
    s += __shfl_xor(s, 16, 64);
    s += __shfl_xor(s, 32, 64);
    if (lane < 16) {
      const float sc = sqrtf(s2) / (z * z);
      io_s[h * 16 + dd2] = s * sc;
    }
  }
  __syncthreads();

  if (tid < 192) {   // equi_out = eo @ equi_out_w
    const int x = tid >> 6, e = tid & 63;
    float a = 0.f;
    for (int d = 0; d < 64; ++d) a += eo_s[x][d] * eow[(size_t)d * 64 + e];
    out[(size_t)bq * 192 + x * 64 + e] = a;
  }
  if (tid < 256) {   // inv_out = io @ inv_out_w + iob
    float a = iob[tid];
    for (int k = 0; k < 256; ++k) a += io_s[k] * iow[(size_t)k * 256 + tid];
    out[98304 + (size_t)bq * 256 + tid] = a;
  }
}

// ===================== launch =====================
extern "C" void kernel_launch(void* const* d_in, const int* in_sizes, int n_in,
                              void* d_out, int out_size, void* d_ws, size_t ws_size,
                              hipStream_t stream) {
  const float* equis      = (const float*)d_in[0];
  const float* invs       = (const float*)d_in[1];
  const float* cond_equis = (const float*)d_in[2];
  const float* cond_invs  = (const float*)d_in[3];
  const float* edges      = (const float*)d_in[4];
  const int*   adj        = (const int*)d_in[5];
  const float* q_w  = (const float*)d_in[6];
  const float* q_b  = (const float*)d_in[7];
  const float* k_w  = (const float*)d_in[8];
  const float* k_b  = (const float*)d_in[9];
  const float* w1   = (const float*)d_in[10];
  const float* b1   = (const float*)d_in[11];
  const float* w2   = (const float*)d_in[12];
  const float* b2   = (const float*)d_in[13];
  const float* equi_in_w  = (const float*)d_in[14];
  const float* equi_out_w = (const float*)d_in[15];
  const float* inv_in_w   = (const float*)d_in[16];
  const float* inv_in_b   = (const float*)d_in[17];
  const float* inv_out_w  = (const float*)d_in[18];
  const float* inv_out_b  = (const float*)d_in[19];

  float* out = (float*)d_out;
  float* ws  = (float*)d_ws;
  unsigned short* w1f = (unsigned short*)ws;               // 65536 us
  unsigned short* w2f = w1f + 65536;                       // 36864 us (-> 51200 floats)
  unsigned short* kmb = (unsigned short*)(ws + 51200);     // 32768 us
  float* hq    = ws + 51200 + 65536;                       // 131072 f  [bq][256]
  float* projt = hq + 131072;                              // 196608 f  [b][x][d][512]
  float* pft   = projt + 196608;                           // 262144 f  [b][ch][512]
  __hip_bfloat16* sct = (__hip_bfloat16*)(pft + 262144);   // 512*80*512 bf16 = 41.9 MB

  prep_all<<<2585, 256, 0, stream>>>(invs, cond_invs, cond_equis,
                                     q_w, q_b, k_w, k_b, w1, b1, w2,
                                     equi_in_w, inv_in_w, inv_in_b,
                                     w1f, w2f, kmb, hq, projt, pft);

  msg_kernel<<<4096, 256, 0, stream>>>(equis, cond_equis, edges, hq, kmb,
                                       w1f, w2f, b2,
                                       out + 229376 /*edge_out*/, sct);

  attn_kernel<<<512, 512, 0, stream>>>(sct, adj, projt, pft,
                                       equi_out_w, inv_out_w, inv_out_b, out);
}